// Round 13
// baseline (121.978 us; speedup 1.0000x reference)
//
#include <hip/hip_runtime.h>

// PositionAttentionModule: B=2, C=64, Cr=8, N=8192
// Single-head attention: d_qk=8, d_v=64, seq=8192 per batch.
// out[b,c,m] = alpha * (sum_n softmax_n(Q[m].K[n]) * V[c,n]) + x[b,c,m]
//
// R13 = R7's proven inner loop (fragment-major V in global, named A/B reg
// buffers, no LDS, no barriers) repackaged for TLP: 128-thread blocks
// (2 waves), each wave = one (q-tile, kg) task; grid 2048 = up to 10
// blocks/CU = 20 waves/CU (unified regfile cap ~21 at ~96 regs/wave).
// kg = blk&7 aligns key-group with XCD L2. Per-kg partials (PO bf16 /
// PD f32) + R12's merge kernel replace the in-block merge tree.
// R10-12's LDS-DMA structure retired: 3 variants all hit a hidden
// register cliff (450MB phantom traffic); this path has none.

#define NB   2
#define CH   64
#define CR   8
#define NPOS 8192

typedef __attribute__((ext_vector_type(8)))  __bf16 bf16x8;
typedef __attribute__((ext_vector_type(16))) float  f32x16;

__device__ inline unsigned pk_bf(float lo, float hi) {
    unsigned r;
    asm("v_cvt_pk_bf16_f32 %0, %1, %2" : "=v"(r) : "v"(lo), "v"(hi));
    return r;
}
__device__ inline unsigned short f2bf(float v) {
    return (unsigned short)(pk_bf(v, 0.f) & 0xFFFFu);
}
__device__ inline float bf2f(unsigned short s) {
    union { unsigned u; float f; } x; x.u = (unsigned)s << 16; return x.f;
}
union U4B { uint4 u; bf16x8 b; };
__device__ inline bf16x8 as_bf(uint4 u) { U4B x; x.u = u; return x.b; }

// ---------------- projection kernel (MFMA, unchanged from R7) ----------------
__global__ __launch_bounds__(128) void proj_kernel(
    const float* __restrict__ x,
    const float* __restrict__ w_b, const float* __restrict__ b_b,
    const float* __restrict__ w_c,
    const float* __restrict__ w_d,
    unsigned short* __restrict__ Qb, unsigned short* __restrict__ Kb,
    unsigned short* __restrict__ VFb)
{
    __shared__ unsigned short wt[96 * 64];
    const int tid = threadIdx.x;
    const float L2E = 1.4426950408889634f;
    for (int j = tid; j < 4096; j += 128) wt[j] = f2bf(w_d[j]);
    for (int j = tid; j < 512; j += 128) {
        wt[64 * 64 + j] = f2bf(w_b[j] * L2E);
        wt[72 * 64 + j] = f2bf(w_c[j]);
    }
    __syncthreads();

    const int w  = tid >> 6, l = tid & 63, li = l & 31, h = l >> 5;
    const int ng = blockIdx.x * 64 + w * 32;
    const int b  = ng >> 13;
    const int n  = ng & (NPOS - 1);

    const f32x16 z16 = {0,0,0,0,0,0,0,0,0,0,0,0,0,0,0,0};

    uint4 af[3][4];
    #pragma unroll
    for (int t = 0; t < 3; ++t)
        #pragma unroll
        for (int ks = 0; ks < 4; ++ks)
            af[t][ks] = *(const uint4*)&wt[(t * 32 + li) * 64 + ks * 16 + 8 * h];

    f32x16 acc0 = z16, acc1 = z16, acc2 = z16;
    #pragma unroll
    for (int ks = 0; ks < 4; ++ks) {
        float xr[8];
        #pragma unroll
        for (int j = 0; j < 8; ++j)
            xr[j] = x[(size_t)(b * CH + ks * 16 + 8 * h + j) * NPOS + n + li];
        uint4 bf = make_uint4(pk_bf(xr[0], xr[1]), pk_bf(xr[2], xr[3]),
                              pk_bf(xr[4], xr[5]), pk_bf(xr[6], xr[7]));
        acc0 = __builtin_amdgcn_mfma_f32_32x32x16_bf16(as_bf(af[0][ks]), as_bf(bf), acc0, 0, 0, 0);
        acc1 = __builtin_amdgcn_mfma_f32_32x32x16_bf16(as_bf(af[1][ks]), as_bf(bf), acc1, 0, 0, 0);
        acc2 = __builtin_amdgcn_mfma_f32_32x32x16_bf16(as_bf(af[2][ks]), as_bf(bf), acc2, 0, 0, 0);
    }

    // V epilogue -> fragment-major: ushort off = kb*2048 + ks*512 + ch*8 + elem
    {
        const int kb = n >> 5;
        const int ks = ((li >> 4) << 1) | ((li >> 3) & 1);
        unsigned short* vf = VFb + (size_t)b * NPOS * CH
                           + (size_t)kb * 2048 + ks * 512 + (li & 7);
        #pragma unroll
        for (int r = 0; r < 16; ++r) {
            int crow = (r & 3) + 8 * (r >> 2) + 4 * h;
            vf[crow * 8]        = f2bf(acc0[r]);
            vf[(32 + crow) * 8] = f2bf(acc1[r]);
        }
    }

    // Q/K epilogue
    {
        float bb0 = b_b[4 * h + 0] * L2E, bb1 = b_b[4 * h + 1] * L2E;
        float bb2 = b_b[4 * h + 2] * L2E, bb3 = b_b[4 * h + 3] * L2E;
        unsigned q0p = pk_bf(acc2[0] + bb0, acc2[1] + bb1);
        unsigned q1p = pk_bf(acc2[2] + bb2, acc2[3] + bb3);
        unsigned k0p = pk_bf(acc2[4], acc2[5]);
        unsigned k1p = pk_bf(acc2[6], acc2[7]);
        unsigned qa0 = q0p, qb0 = q0p, qa1 = q1p, qb1 = q1p;
        asm("v_permlane32_swap_b32 %0, %1" : "+v"(qa0), "+v"(qb0));
        asm("v_permlane32_swap_b32 %0, %1" : "+v"(qa1), "+v"(qb1));
        unsigned ka0 = k0p, kb0 = k0p, ka1 = k1p, kb1 = k1p;
        asm("v_permlane32_swap_b32 %0, %1" : "+v"(ka0), "+v"(kb0));
        asm("v_permlane32_swap_b32 %0, %1" : "+v"(ka1), "+v"(kb1));
        if (h == 0) {
            *(uint4*)(Qb + (size_t)(b * NPOS + n + li) * CR) = make_uint4(qa0, qa1, qb0, qb1);
            *(uint4*)(Kb + (size_t)(b * NPOS + n + li) * CR) = make_uint4(ka0, ka1, kb0, kb1);
        }
    }
}

// ---------------- fused MFMA flash-attention (2-wave blocks, barrier-free) ---
// grid = 2048 blocks x 128 thr. Block: kg = blk&7 (XCD-aligned), qt-pair,
// batch b. Wave w handles q-tile qt2*2+w (32 queries) x keys [kg*1024,+1024).
__global__ __launch_bounds__(128, 5) void attn_kernel(
    const unsigned short* __restrict__ Qb, const unsigned short* __restrict__ Kb,
    const unsigned short* __restrict__ VFb,
    unsigned short* __restrict__ PO, float* __restrict__ PD)
{
    const int tid = threadIdx.x;
    const int w   = tid >> 6;
    const int l   = tid & 63;
    const int li  = l & 31;
    const int h   = l >> 5;
    const int blk = blockIdx.x;
    const int kg  = blk & 7;               // key group == XCD (blocks round-robin)
    const int qt2 = (blk >> 3) & 127;      // q-tile pair
    const int b   = blk >> 10;
    const int m   = (qt2 * 2 + w) * 32 + li;   // this wave's queries

    const f32x16 z16 = {0,0,0,0,0,0,0,0,0,0,0,0,0,0,0,0};
    const uint4 zero4 = make_uint4(0, 0, 0, 0);

    uint4 qf = zero4;
    if (h == 0) qf = *(const uint4*)(Qb + ((size_t)b * NPOS + m) * CR);

    f32x16 acc0 = z16, acc1 = z16;
    float dn0 = 0.f, dn1 = 0.f, dn2 = 0.f, dn3 = 0.f;

    // K rows: wave keys = kg*1024 + cc*32 + li
    const unsigned short* kbp = Kb + ((size_t)b * NPOS + kg * 1024 + li) * CR;
    // V fragments: ushort off = keyblock*2048 + (2j+h)*512 + ch*8 + elem
    const unsigned short* vfb = VFb + (size_t)b * NPOS * CH
                              + (size_t)kg * 32 * 2048 + h * 512 + li * 8;

#define LOADS(CC, KF, A00, A01, A10, A11) {                        \
    const unsigned short* vp_ = vfb + (size_t)(CC) * 2048;         \
    A00 = *(const uint4*)(vp_);                                    \
    A01 = *(const uint4*)(vp_ + 1024);                             \
    A10 = *(const uint4*)(vp_ + 256);                              \
    A11 = *(const uint4*)(vp_ + 1280);                             \
    KF = zero4;                                                    \
    if (h == 0) KF = *(const uint4*)(kbp + (size_t)(CC) * 32 * CR); }

#define COMPUTE(KF, A00, A01, A10, A11) {                                                     \
    f32x16 sv = __builtin_amdgcn_mfma_f32_32x32x16_bf16(as_bf(KF), as_bf(qf), z16, 0, 0, 0);  \
    float p0_, p1_;                                                                           \
    unsigned pa0, pa1, pb0, pb1, pc0, pc1, pd0, pd1;                                          \
    p0_ = __builtin_amdgcn_exp2f(sv[0]);  p1_ = __builtin_amdgcn_exp2f(sv[1]);                \
    dn0 += p0_ + p1_;  pa0 = pk_bf(p0_, p1_);                                                 \
    p0_ = __builtin_amdgcn_exp2f(sv[2]);  p1_ = __builtin_amdgcn_exp2f(sv[3]);                \
    dn1 += p0_ + p1_;  pa1 = pk_bf(p0_, p1_);                                                 \
    p0_ = __builtin_amdgcn_exp2f(sv[4]);  p1_ = __builtin_amdgcn_exp2f(sv[5]);                \
    dn2 += p0_ + p1_;  pb0 = pk_bf(p0_, p1_);                                                 \
    p0_ = __builtin_amdgcn_exp2f(sv[6]);  p1_ = __builtin_amdgcn_exp2f(sv[7]);                \
    dn3 += p0_ + p1_;  pb1 = pk_bf(p0_, p1_);                                                 \
    p0_ = __builtin_amdgcn_exp2f(sv[8]);  p1_ = __builtin_amdgcn_exp2f(sv[9]);                \
    dn0 += p0_ + p1_;  pc0 = pk_bf(p0_, p1_);                                                 \
    p0_ = __builtin_amdgcn_exp2f(sv[10]); p1_ = __builtin_amdgcn_exp2f(sv[11]);               \
    dn1 += p0_ + p1_;  pc1 = pk_bf(p0_, p1_);                                                 \
    p0_ = __builtin_amdgcn_exp2f(sv[12]); p1_ = __builtin_amdgcn_exp2f(sv[13]);               \
    dn2 += p0_ + p1_;  pd0 = pk_bf(p0_, p1_);                                                 \
    p0_ = __builtin_amdgcn_exp2f(sv[14]); p1_ = __builtin_amdgcn_exp2f(sv[15]);               \
    dn3 += p0_ + p1_;  pd1 = pk_bf(p0_, p1_);                                                 \
    asm("v_permlane32_swap_b32 %0, %1" : "+v"(pa0), "+v"(pb0));                               \
    asm("v_permlane32_swap_b32 %0, %1" : "+v"(pa1), "+v"(pb1));                               \
    asm("v_permlane32_swap_b32 %0, %1" : "+v"(pc0), "+v"(pd0));                               \
    asm("v_permlane32_swap_b32 %0, %1" : "+v"(pc1), "+v"(pd1));                               \
    uint4 BA = make_uint4(pa0, pa1, pb0, pb1);                                                \
    uint4 BB = make_uint4(pc0, pc1, pd0, pd1);                                                \
    acc0 = __builtin_amdgcn_mfma_f32_32x32x16_bf16(as_bf(A00), as_bf(BA), acc0, 0, 0, 0);     \
    acc0 = __builtin_amdgcn_mfma_f32_32x32x16_bf16(as_bf(A01), as_bf(BB), acc0, 0, 0, 0);     \
    acc1 = __builtin_amdgcn_mfma_f32_32x32x16_bf16(as_bf(A10), as_bf(BA), acc1, 0, 0, 0);     \
    acc1 = __builtin_amdgcn_mfma_f32_32x32x16_bf16(as_bf(A11), as_bf(BB), acc1, 0, 0, 0); }

    uint4 kfA, a00A, a01A, a10A, a11A;
    uint4 kfB, a00B, a01B, a10B, a11B;
    LOADS(0, kfA, a00A, a01A, a10A, a11A);

    for (int cc = 0; cc < 32; cc += 2) {
        LOADS(cc + 1, kfB, a00B, a01B, a10B, a11B);
        COMPUTE(kfA, a00A, a01A, a10A, a11A);
        if (cc + 2 < 32) LOADS(cc + 2, kfA, a00A, a01A, a10A, a11A);
        COMPUTE(kfB, a00B, a01B, a10B, a11B);
    }
#undef LOADS
#undef COMPUTE

    float den = (dn0 + dn1) + (dn2 + dn3);
    den += __shfl_xor(den, 32);        // other half holds the other 16 key-rows

    // ---- write per-kg partials: PO bf16 [g=kg*2+b][64ch][8192q], PD f32 [g][8192] ----
    {
        const int g = kg * 2 + b;
        #pragma unroll
        for (int r = 0; r < 16; ++r) {
            int crow = (r & 3) + 8 * (r >> 2) + 4 * h;
            PO[((size_t)g * 64 + crow) * NPOS + m]      = f2bf(acc0[r]);
            PO[((size_t)g * 64 + 32 + crow) * NPOS + m] = f2bf(acc1[r]);
        }
        if (h == 0) PD[(size_t)g * NPOS + m] = den;
    }
}

// ---------------- merge kernel: sum 8 kg-groups, normalize, + alpha*b_d + x ----
__global__ __launch_bounds__(256) void merge_kernel(
    const unsigned short* __restrict__ PO, const float* __restrict__ PD,
    const float* __restrict__ x, const float* __restrict__ alpha,
    const float* __restrict__ b_d, float* __restrict__ out)
{
    const int t  = blockIdx.x * 256 + threadIdx.x;   // 0 .. 262143
    const int q4 = (t & 2047) * 4;
    const int bc = t >> 11;                          // b*64 + c
    const int b  = bc >> 6, c = bc & 63;

    float4 o = make_float4(0.f, 0.f, 0.f, 0.f);
    float4 d = make_float4(0.f, 0.f, 0.f, 0.f);
    #pragma unroll
    for (int kg = 0; kg < 8; ++kg) {
        const int g = kg * 2 + b;
        ushort4 u = *(const ushort4*)(PO + ((size_t)g * 64 + c) * NPOS + q4);
        o.x += bf2f(u.x); o.y += bf2f(u.y); o.z += bf2f(u.z); o.w += bf2f(u.w);
        float4 dv = *(const float4*)(PD + (size_t)g * NPOS + q4);
        d.x += dv.x; d.y += dv.y; d.z += dv.z; d.w += dv.w;
    }
    const float al = alpha[0];
    const float albd = al * b_d[c];
    const size_t xo = ((size_t)bc << 13) + q4;
    float4 xv = *(const float4*)&x[xo];
    float4 r;
    r.x = o.x * (al / d.x) + albd + xv.x;
    r.y = o.y * (al / d.y) + albd + xv.y;
    r.z = o.z * (al / d.z) + albd + xv.z;
    r.w = o.w * (al / d.w) + albd + xv.w;
    *(float4*)&out[xo] = r;
}

extern "C" void kernel_launch(void* const* d_in, const int* in_sizes, int n_in,
                              void* d_out, int out_size, void* d_ws, size_t ws_size,
                              hipStream_t stream) {
    const float* x     = (const float*)d_in[0];
    const float* w_b   = (const float*)d_in[1];
    const float* b_b   = (const float*)d_in[2];
    const float* w_c   = (const float*)d_in[3];
    // d_in[4] = b_c: dropped exactly (softmax-invariant per-query constant).
    const float* w_d   = (const float*)d_in[5];
    const float* b_d   = (const float*)d_in[6];
    const float* alpha = (const float*)d_in[7];
    float* out = (float*)d_out;

    unsigned short* Qw  = (unsigned short*)d_ws;                 // 256 KB
    unsigned short* Kw  = Qw + (size_t)NB * NPOS * CR;           // 256 KB
    unsigned short* VFw = Kw + (size_t)NB * NPOS * CR;           // 2 MB (frag-major)
    unsigned short* PO  = VFw + (size_t)NB * NPOS * CH;          // 16.8 MB (bf16 partial O)
    float*          PD  = (float*)(PO + (size_t)16 * CH * NPOS); // 512 KB (f32 partial den)

    proj_kernel<<<256, 128, 0, stream>>>(x, w_b, b_b, w_c, w_d, Qw, Kw, VFw);
    attn_kernel<<<2048, 128, 0, stream>>>(Qw, Kw, VFw, PO, PD);
    merge_kernel<<<1024, 256, 0, stream>>>(PO, PD, x, alpha, b_d, out);
}

// Round 14
// 63.003 us; speedup vs baseline: 1.9361x; 1.9361x over previous
//
#include <hip/hip_runtime.h>

// PositionAttentionModule: B=2, C=64, Cr=8, N=8192
// Single-head attention: d_qk=8, d_v=64, seq=8192 per batch.
// out[b,c,m] = alpha * (sum_n softmax_n(Q[m].K[n]) * V[c,n]) + x[b,c,m]
//
// R14 = R13 with __launch_bounds__(128) -- NO min-waves arg. Evidence:
// (1024,8)->32 VGPR spill (R8), (128,5)->48 VGPR spill (R13); the proven
// clean allocation (R7/R9) is the allocator's NATURAL 64-VGPR choice.
// Structure: 2-wave blocks, grid 2048 (kg 0..7 == XCD, q-tile pairs),
// fragment-major V in global, barrier-free, PO/PD partials + merge kernel.
// Natural ~96 unified regs/wave + LDS=0 admits ~20 waves/CU (vs 16 in R7):
// this round isolates the TLP lever with zero allocator coercion.

#define NB   2
#define CH   64
#define CR   8
#define NPOS 8192

typedef __attribute__((ext_vector_type(8)))  __bf16 bf16x8;
typedef __attribute__((ext_vector_type(16))) float  f32x16;

__device__ inline unsigned pk_bf(float lo, float hi) {
    unsigned r;
    asm("v_cvt_pk_bf16_f32 %0, %1, %2" : "=v"(r) : "v"(lo), "v"(hi));
    return r;
}
__device__ inline unsigned short f2bf(float v) {
    return (unsigned short)(pk_bf(v, 0.f) & 0xFFFFu);
}
__device__ inline float bf2f(unsigned short s) {
    union { unsigned u; float f; } x; x.u = (unsigned)s << 16; return x.f;
}
union U4B { uint4 u; bf16x8 b; };
__device__ inline bf16x8 as_bf(uint4 u) { U4B x; x.u = u; return x.b; }

// ---------------- projection kernel (MFMA, unchanged from R7) ----------------
__global__ __launch_bounds__(128) void proj_kernel(
    const float* __restrict__ x,
    const float* __restrict__ w_b, const float* __restrict__ b_b,
    const float* __restrict__ w_c,
    const float* __restrict__ w_d,
    unsigned short* __restrict__ Qb, unsigned short* __restrict__ Kb,
    unsigned short* __restrict__ VFb)
{
    __shared__ unsigned short wt[96 * 64];
    const int tid = threadIdx.x;
    const float L2E = 1.4426950408889634f;
    for (int j = tid; j < 4096; j += 128) wt[j] = f2bf(w_d[j]);
    for (int j = tid; j < 512; j += 128) {
        wt[64 * 64 + j] = f2bf(w_b[j] * L2E);
        wt[72 * 64 + j] = f2bf(w_c[j]);
    }
    __syncthreads();

    const int w  = tid >> 6, l = tid & 63, li = l & 31, h = l >> 5;
    const int ng = blockIdx.x * 64 + w * 32;
    const int b  = ng >> 13;
    const int n  = ng & (NPOS - 1);

    const f32x16 z16 = {0,0,0,0,0,0,0,0,0,0,0,0,0,0,0,0};

    uint4 af[3][4];
    #pragma unroll
    for (int t = 0; t < 3; ++t)
        #pragma unroll
        for (int ks = 0; ks < 4; ++ks)
            af[t][ks] = *(const uint4*)&wt[(t * 32 + li) * 64 + ks * 16 + 8 * h];

    f32x16 acc0 = z16, acc1 = z16, acc2 = z16;
    #pragma unroll
    for (int ks = 0; ks < 4; ++ks) {
        float xr[8];
        #pragma unroll
        for (int j = 0; j < 8; ++j)
            xr[j] = x[(size_t)(b * CH + ks * 16 + 8 * h + j) * NPOS + n + li];
        uint4 bf = make_uint4(pk_bf(xr[0], xr[1]), pk_bf(xr[2], xr[3]),
                              pk_bf(xr[4], xr[5]), pk_bf(xr[6], xr[7]));
        acc0 = __builtin_amdgcn_mfma_f32_32x32x16_bf16(as_bf(af[0][ks]), as_bf(bf), acc0, 0, 0, 0);
        acc1 = __builtin_amdgcn_mfma_f32_32x32x16_bf16(as_bf(af[1][ks]), as_bf(bf), acc1, 0, 0, 0);
        acc2 = __builtin_amdgcn_mfma_f32_32x32x16_bf16(as_bf(af[2][ks]), as_bf(bf), acc2, 0, 0, 0);
    }

    // V epilogue -> fragment-major: ushort off = kb*2048 + ks*512 + ch*8 + elem
    {
        const int kb = n >> 5;
        const int ks = ((li >> 4) << 1) | ((li >> 3) & 1);
        unsigned short* vf = VFb + (size_t)b * NPOS * CH
                           + (size_t)kb * 2048 + ks * 512 + (li & 7);
        #pragma unroll
        for (int r = 0; r < 16; ++r) {
            int crow = (r & 3) + 8 * (r >> 2) + 4 * h;
            vf[crow * 8]        = f2bf(acc0[r]);
            vf[(32 + crow) * 8] = f2bf(acc1[r]);
        }
    }

    // Q/K epilogue
    {
        float bb0 = b_b[4 * h + 0] * L2E, bb1 = b_b[4 * h + 1] * L2E;
        float bb2 = b_b[4 * h + 2] * L2E, bb3 = b_b[4 * h + 3] * L2E;
        unsigned q0p = pk_bf(acc2[0] + bb0, acc2[1] + bb1);
        unsigned q1p = pk_bf(acc2[2] + bb2, acc2[3] + bb3);
        unsigned k0p = pk_bf(acc2[4], acc2[5]);
        unsigned k1p = pk_bf(acc2[6], acc2[7]);
        unsigned qa0 = q0p, qb0 = q0p, qa1 = q1p, qb1 = q1p;
        asm("v_permlane32_swap_b32 %0, %1" : "+v"(qa0), "+v"(qb0));
        asm("v_permlane32_swap_b32 %0, %1" : "+v"(qa1), "+v"(qb1));
        unsigned ka0 = k0p, kb0 = k0p, ka1 = k1p, kb1 = k1p;
        asm("v_permlane32_swap_b32 %0, %1" : "+v"(ka0), "+v"(kb0));
        asm("v_permlane32_swap_b32 %0, %1" : "+v"(ka1), "+v"(kb1));
        if (h == 0) {
            *(uint4*)(Qb + (size_t)(b * NPOS + n + li) * CR) = make_uint4(qa0, qa1, qb0, qb1);
            *(uint4*)(Kb + (size_t)(b * NPOS + n + li) * CR) = make_uint4(ka0, ka1, kb0, kb1);
        }
    }
}

// ---------------- fused MFMA flash-attention (2-wave blocks, barrier-free) ---
// grid = 2048 blocks x 128 thr. Block: kg = blk&7 (XCD-aligned), qt-pair,
// batch b. Wave w handles q-tile qt2*2+w (32 queries) x keys [kg*1024,+1024).
__global__ __launch_bounds__(128) void attn_kernel(
    const unsigned short* __restrict__ Qb, const unsigned short* __restrict__ Kb,
    const unsigned short* __restrict__ VFb,
    unsigned short* __restrict__ PO, float* __restrict__ PD)
{
    const int tid = threadIdx.x;
    const int w   = tid >> 6;
    const int l   = tid & 63;
    const int li  = l & 31;
    const int h   = l >> 5;
    const int blk = blockIdx.x;
    const int kg  = blk & 7;               // key group == XCD (blocks round-robin)
    const int qt2 = (blk >> 3) & 127;      // q-tile pair
    const int b   = blk >> 10;
    const int m   = (qt2 * 2 + w) * 32 + li;   // this wave's queries

    const f32x16 z16 = {0,0,0,0,0,0,0,0,0,0,0,0,0,0,0,0};
    const uint4 zero4 = make_uint4(0, 0, 0, 0);

    uint4 qf = zero4;
    if (h == 0) qf = *(const uint4*)(Qb + ((size_t)b * NPOS + m) * CR);

    f32x16 acc0 = z16, acc1 = z16;
    float dn0 = 0.f, dn1 = 0.f, dn2 = 0.f, dn3 = 0.f;

    // K rows: wave keys = kg*1024 + cc*32 + li
    const unsigned short* kbp = Kb + ((size_t)b * NPOS + kg * 1024 + li) * CR;
    // V fragments: ushort off = keyblock*2048 + (2j+h)*512 + ch*8 + elem
    const unsigned short* vfb = VFb + (size_t)b * NPOS * CH
                              + (size_t)kg * 32 * 2048 + h * 512 + li * 8;

#define LOADS(CC, KF, A00, A01, A10, A11) {                        \
    const unsigned short* vp_ = vfb + (size_t)(CC) * 2048;         \
    A00 = *(const uint4*)(vp_);                                    \
    A01 = *(const uint4*)(vp_ + 1024);                             \
    A10 = *(const uint4*)(vp_ + 256);                              \
    A11 = *(const uint4*)(vp_ + 1280);                             \
    KF = zero4;                                                    \
    if (h == 0) KF = *(const uint4*)(kbp + (size_t)(CC) * 32 * CR); }

#define COMPUTE(KF, A00, A01, A10, A11) {                                                     \
    f32x16 sv = __builtin_amdgcn_mfma_f32_32x32x16_bf16(as_bf(KF), as_bf(qf), z16, 0, 0, 0);  \
    float p0_, p1_;                                                                           \
    unsigned pa0, pa1, pb0, pb1, pc0, pc1, pd0, pd1;                                          \
    p0_ = __builtin_amdgcn_exp2f(sv[0]);  p1_ = __builtin_amdgcn_exp2f(sv[1]);                \
    dn0 += p0_ + p1_;  pa0 = pk_bf(p0_, p1_);                                                 \
    p0_ = __builtin_amdgcn_exp2f(sv[2]);  p1_ = __builtin_amdgcn_exp2f(sv[3]);                \
    dn1 += p0_ + p1_;  pa1 = pk_bf(p0_, p1_);                                                 \
    p0_ = __builtin_amdgcn_exp2f(sv[4]);  p1_ = __builtin_amdgcn_exp2f(sv[5]);                \
    dn2 += p0_ + p1_;  pb0 = pk_bf(p0_, p1_);                                                 \
    p0_ = __builtin_amdgcn_exp2f(sv[6]);  p1_ = __builtin_amdgcn_exp2f(sv[7]);                \
    dn3 += p0_ + p1_;  pb1 = pk_bf(p0_, p1_);                                                 \
    p0_ = __builtin_amdgcn_exp2f(sv[8]);  p1_ = __builtin_amdgcn_exp2f(sv[9]);                \
    dn0 += p0_ + p1_;  pc0 = pk_bf(p0_, p1_);                                                 \
    p0_ = __builtin_amdgcn_exp2f(sv[10]); p1_ = __builtin_amdgcn_exp2f(sv[11]);               \
    dn1 += p0_ + p1_;  pc1 = pk_bf(p0_, p1_);                                                 \
    p0_ = __builtin_amdgcn_exp2f(sv[12]); p1_ = __builtin_amdgcn_exp2f(sv[13]);               \
    dn2 += p0_ + p1_;  pd0 = pk_bf(p0_, p1_);                                                 \
    p0_ = __builtin_amdgcn_exp2f(sv[14]); p1_ = __builtin_amdgcn_exp2f(sv[15]);               \
    dn3 += p0_ + p1_;  pd1 = pk_bf(p0_, p1_);                                                 \
    asm("v_permlane32_swap_b32 %0, %1" : "+v"(pa0), "+v"(pb0));                               \
    asm("v_permlane32_swap_b32 %0, %1" : "+v"(pa1), "+v"(pb1));                               \
    asm("v_permlane32_swap_b32 %0, %1" : "+v"(pc0), "+v"(pd0));                               \
    asm("v_permlane32_swap_b32 %0, %1" : "+v"(pc1), "+v"(pd1));                               \
    uint4 BA = make_uint4(pa0, pa1, pb0, pb1);                                                \
    uint4 BB = make_uint4(pc0, pc1, pd0, pd1);                                                \
    acc0 = __builtin_amdgcn_mfma_f32_32x32x16_bf16(as_bf(A00), as_bf(BA), acc0, 0, 0, 0);     \
    acc0 = __builtin_amdgcn_mfma_f32_32x32x16_bf16(as_bf(A01), as_bf(BB), acc0, 0, 0, 0);     \
    acc1 = __builtin_amdgcn_mfma_f32_32x32x16_bf16(as_bf(A10), as_bf(BA), acc1, 0, 0, 0);     \
    acc1 = __builtin_amdgcn_mfma_f32_32x32x16_bf16(as_bf(A11), as_bf(BB), acc1, 0, 0, 0); }

    uint4 kfA, a00A, a01A, a10A, a11A;
    uint4 kfB, a00B, a01B, a10B, a11B;
    LOADS(0, kfA, a00A, a01A, a10A, a11A);

    for (int cc = 0; cc < 32; cc += 2) {
        LOADS(cc + 1, kfB, a00B, a01B, a10B, a11B);
        COMPUTE(kfA, a00A, a01A, a10A, a11A);
        if (cc + 2 < 32) LOADS(cc + 2, kfA, a00A, a01A, a10A, a11A);
        COMPUTE(kfB, a00B, a01B, a10B, a11B);
    }
#undef LOADS
#undef COMPUTE

    float den = (dn0 + dn1) + (dn2 + dn3);
    den += __shfl_xor(den, 32);        // other half holds the other 16 key-rows

    // ---- write per-kg partials: PO bf16 [g=kg*2+b][64ch][8192q], PD f32 [g][8192] ----
    {
        const int g = kg * 2 + b;
        #pragma unroll
        for (int r = 0; r < 16; ++r) {
            int crow = (r & 3) + 8 * (r >> 2) + 4 * h;
            PO[((size_t)g * 64 + crow) * NPOS + m]      = f2bf(acc0[r]);
            PO[((size_t)g * 64 + 32 + crow) * NPOS + m] = f2bf(acc1[r]);
        }
        if (h == 0) PD[(size_t)g * NPOS + m] = den;
    }
}

// ---------------- merge kernel: sum 8 kg-groups, normalize, + alpha*b_d + x ----
__global__ __launch_bounds__(256) void merge_kernel(
    const unsigned short* __restrict__ PO, const float* __restrict__ PD,
    const float* __restrict__ x, const float* __restrict__ alpha,
    const float* __restrict__ b_d, float* __restrict__ out)
{
    const int t  = blockIdx.x * 256 + threadIdx.x;   // 0 .. 262143
    const int q4 = (t & 2047) * 4;
    const int bc = t >> 11;                          // b*64 + c
    const int b  = bc >> 6, c = bc & 63;

    float4 o = make_float4(0.f, 0.f, 0.f, 0.f);
    float4 d = make_float4(0.f, 0.f, 0.f, 0.f);
    #pragma unroll
    for (int kg = 0; kg < 8; ++kg) {
        const int g = kg * 2 + b;
        ushort4 u = *(const ushort4*)(PO + ((size_t)g * 64 + c) * NPOS + q4);
        o.x += bf2f(u.x); o.y += bf2f(u.y); o.z += bf2f(u.z); o.w += bf2f(u.w);
        float4 dv = *(const float4*)(PD + (size_t)g * NPOS + q4);
        d.x += dv.x; d.y += dv.y; d.z += dv.z; d.w += dv.w;
    }
    const float al = alpha[0];
    const float albd = al * b_d[c];
    const size_t xo = ((size_t)bc << 13) + q4;
    float4 xv = *(const float4*)&x[xo];
    float4 r;
    r.x = o.x * (al / d.x) + albd + xv.x;
    r.y = o.y * (al / d.y) + albd + xv.y;
    r.z = o.z * (al / d.z) + albd + xv.z;
    r.w = o.w * (al / d.w) + albd + xv.w;
    *(float4*)&out[xo] = r;
}

extern "C" void kernel_launch(void* const* d_in, const int* in_sizes, int n_in,
                              void* d_out, int out_size, void* d_ws, size_t ws_size,
                              hipStream_t stream) {
    const float* x     = (const float*)d_in[0];
    const float* w_b   = (const float*)d_in[1];
    const float* b_b   = (const float*)d_in[2];
    const float* w_c   = (const float*)d_in[3];
    // d_in[4] = b_c: dropped exactly (softmax-invariant per-query constant).
    const float* w_d   = (const float*)d_in[5];
    const float* b_d   = (const float*)d_in[6];
    const float* alpha = (const float*)d_in[7];
    float* out = (float*)d_out;

    unsigned short* Qw  = (unsigned short*)d_ws;                 // 256 KB
    unsigned short* Kw  = Qw + (size_t)NB * NPOS * CR;           // 256 KB
    unsigned short* VFw = Kw + (size_t)NB * NPOS * CR;           // 2 MB (frag-major)
    unsigned short* PO  = VFw + (size_t)NB * NPOS * CH;          // 16.8 MB (bf16 partial O)
    float*          PD  = (float*)(PO + (size_t)16 * CH * NPOS); // 512 KB (f32 partial den)

    proj_kernel<<<256, 128, 0, stream>>>(x, w_b, b_b, w_c, w_d, Qw, Kw, VFw);
    attn_kernel<<<2048, 128, 0, stream>>>(Qw, Kw, VFw, PO, PD);
    merge_kernel<<<1024, 256, 0, stream>>>(PO, PD, x, alpha, b_d, out);
}